// Round 14
// baseline (101.217 us; speedup 1.0000x reference)
//
#include <hip/hip_runtime.h>
#include <math.h>

// B=256, P=40, S=60, D=64. Register-resident MFMA chain, weights in LDS.
// Round-14: R13 hit 228 VGPR because the compiler software-pipelines the
// NEXT part's load_x (16 global_load_dwordx4) across the loop back-edge
// (~+70-100 live VGPRs) -> 2 waves/SIMD -> latency-exposed (occ 9%).
// Fix: __builtin_amdgcn_sched_barrier(0) at the top of the part loop:
// blocks all instruction motion across the back-edge, pinning in-loop
// liveness at the structural ~160 (xf+qf+kf+acc at the scores GEMM).
// Target: <=170 VGPR -> 3 waves/SIMD; 640 WGs = 2.5 WGs/CU co-resident.
//
// Register-chain trick: MFMA contraction is invariant to permuting the k-dim.
// C/D output holds the row-dim in-lane as {16mt+4g+j}; the next GEMM
// contracting that dim takes both operands by pure register reindexing:
//     frag[t][ks] = pk16( acc[2ks][t], acc[2ks+1][t] )
// map pi(ks,i,g)=16*(2ks+(i>>2))+4g+(i&3). W1/W2 pre-permuted to pi-layout.
//
// Layout facts (cdna4 guide, measured m89/m91):
//   C/D: lane holds col=lane&15, rows 16mt+4(lane>>4)+j
//   A/B: row(col)=lane&15, kappa = 32ks+8(lane>>4)+i

typedef _Float16 half8 __attribute__((ext_vector_type(8)));
typedef __fp16 fp16x2 __attribute__((ext_vector_type(2)));
typedef float f4 __attribute__((ext_vector_type(4)));

#define MFMA16(a, b, c) __builtin_amdgcn_mfma_f32_16x16x32_f16((a), (b), (c), 0, 0, 0)

__global__ __launch_bounds__(256) void prep_weights(
    const float* __restrict__ Wq, const float* __restrict__ Wk,
    const float* __restrict__ Wv, const float* __restrict__ W1,
    const float* __restrict__ W2, _Float16* __restrict__ wsH) {
    int idx = blockIdx.x * 256 + threadIdx.x;  // 0..20479
    int m = idx >> 12, r = idx & 4095;
    const float* src = (m == 0) ? Wq : (m == 1) ? Wk : (m == 2) ? Wv
                        : (m == 3) ? W1 : W2;
    float v;
    if (m < 3) {
        v = src[r];  // natural row-major [e][d]
    } else {
        // pi-permuted: position (e, kappa) holds W[e][ d=16*(2ks+(i>>2))+4g+(i&3) ]
        int e = r >> 6, kp = r & 63;
        int ks = kp >> 5, gg = (kp >> 3) & 3, i = kp & 7;
        int d = 16 * (2 * ks + (i >> 2)) + 4 * gg + (i & 3);
        v = src[e * 64 + d];
    }
    wsH[idx] = (_Float16)v;
}

// Packed f32x4 + f32x4 -> half8 via v_cvt_pkrtz_f16_f32 (4 insts).
__device__ __forceinline__ half8 pk8(f4 a, f4 b) {
    union { half8 h; fp16x2 p[4]; } u;
    u.p[0] = __builtin_amdgcn_cvt_pkrtz(a[0], a[1]);
    u.p[1] = __builtin_amdgcn_cvt_pkrtz(a[2], a[3]);
    u.p[2] = __builtin_amdgcn_cvt_pkrtz(b[0], b[1]);
    u.p[3] = __builtin_amdgcn_cvt_pkrtz(b[2], b[3]);
    return u.h;
}

// acc -> pi-layout fragments (optional relu; bias already folded via C-in).
template <bool RELU>
__device__ __forceinline__ void mk_frags(half8 fr[4][2], f4 acc[4][4]) {
    #pragma unroll
    for (int t = 0; t < 4; ++t)
        #pragma unroll
        for (int ks = 0; ks < 2; ++ks) {
            f4 a = acc[2 * ks][t], b = acc[2 * ks + 1][t];
            if (RELU) {
                #pragma unroll
                for (int j = 0; j < 4; ++j) {
                    a[j] = fmaxf(a[j], 0.f);
                    b[j] = fmaxf(b[j], 0.f);
                }
            }
            fr[t][ks] = pk8(a, b);
        }
}

__device__ __forceinline__ void load_x(half8 xf[4][2], const float* __restrict__ xp,
                                       int lo, int g) {
    #pragma unroll
    for (int t = 0; t < 4; ++t) {
        int r = 16 * t + lo;
        #pragma unroll
        for (int ks = 0; ks < 2; ++ks) {
            if (r < 60) {
                const float* p = xp + r * 64 + ks * 32 + g * 8;
                xf[t][ks] = pk8(*(const f4*)p, *(const f4*)(p + 4));
            } else {
                half8 z = {};
                xf[t][ks] = z;
            }
        }
    }
}

// CEXPR is the C operand of the FIRST K-step (bias quad or zc); uses mt, nt.
#define GEMM(AEXPR, BEXPR, CEXPR)                                            \
    do {                                                                     \
        _Pragma("unroll")                                                    \
        for (int ks = 0; ks < 2; ++ks) {                                     \
            half8 afr[4], bfr[4];                                            \
            _Pragma("unroll")                                                \
            for (int t = 0; t < 4; ++t) { afr[t] = (AEXPR); bfr[t] = (BEXPR); } \
            _Pragma("unroll")                                                \
            for (int mt = 0; mt < 4; ++mt)                                   \
                _Pragma("unroll")                                            \
                for (int nt = 0; nt < 4; ++nt)                               \
                    acc[mt][nt] = MFMA16(afr[mt], bfr[nt],                   \
                                         ks == 0 ? (CEXPR) : acc[mt][nt]);   \
        }                                                                    \
    } while (0)

// LDS weight fragment read: element (row=16t+lo, kappa=32ks+8g) of matrix widx,
// 16B chunk XOR-swizzled by (lo&7)<<3 halves (row&7 == lo&7 since 16t%8==0).
#define LFR(widx) (*(const half8*)&wlds[(widx) * 4096 + (16 * t + lo) * 64 + \
                                        ((32 * ks + 8 * g) ^ ((lo & 7) << 3))])

__global__ __launch_bounds__(256, 1) void fused_f16(
    const float* __restrict__ x, const _Float16* __restrict__ wH,
    const float* __restrict__ bq, const float* __restrict__ bk,
    const float* __restrict__ bv, const float* __restrict__ b1,
    const float* __restrict__ b2, const float* __restrict__ W3,
    const float* __restrict__ b3, float* __restrict__ out) {
    __shared__ __align__(16) _Float16 wlds[5 * 4096];  // 40 KB

    const int tid = threadIdx.x;
    const int l = tid & 63;           // lane
    const int w = tid >> 6;           // wave 0..3
    const int lo = l & 15, g = l >> 4;

    // ---- cooperative weight load global->LDS with write-side swizzle:
    // dst halfidx = widx*4096 + row*64 + ((c*8) ^ ((row&7)<<3)), c = 16B chunk.
    #pragma unroll
    for (int rep = 0; rep < 10; ++rep) {
        int chunk = rep * 256 + tid;          // 0..2559
        int widx = chunk >> 9;
        int rem = chunk & 511;
        int row = rem >> 3, c = rem & 7;
        *(half8*)&wlds[widx * 4096 + row * 64 + ((c * 8) ^ ((row & 7) << 3))] =
            *(const half8*)&wH[widx * 4096 + row * 64 + c * 8];
    }
    __syncthreads();  // only barrier; waves independent afterwards

    const int part0 = blockIdx.x * 16 + w * 4;
    const f4 zc = {0.f, 0.f, 0.f, 0.f};

    #pragma unroll 1
    for (int it = 0; it < 4; ++it) {
        // Pin the schedule at the back-edge: nothing from iteration it+1
        // (especially load_x's 16 global loads) may move into iteration it.
        // This is what keeps in-loop liveness ~160 instead of R13's 228.
        __builtin_amdgcn_sched_barrier(0);

        const int part = part0 + it;
        const float* __restrict__ xp = x + (size_t)part * (60 * 64);

        f4 acc[4][4];
        f4 brow[4];
        half8 xf[4][2], qf[4][2], kf[4][2], vf[4][2], pf[4][2], wtf[4][2],
              h1f[4][2];

        load_x(xf, xp, lo, g);

        // ---- qT = Wq * xT + bq (bias via C-in; rows of D are features)
        #pragma unroll
        for (int mt = 0; mt < 4; ++mt) brow[mt] = *(const f4*)&bq[16 * mt + 4 * g];
        GEMM(LFR(0), xf[t][ks], brow[mt]);
        mk_frags<false>(qf, acc);

        // ---- kT = Wk * xT + bk
        #pragma unroll
        for (int mt = 0; mt < 4; ++mt) brow[mt] = *(const f4*)&bk[16 * mt + 4 * g];
        GEMM(LFR(1), xf[t][ks], brow[mt]);
        mk_frags<false>(kf, acc);

        // ---- scoresT[c][s] = sum_d k[c][d] q[s][d]
        GEMM(kf[t][ks], qf[t][ks], zc);

        // ---- softmax over c, scale 1/8 folded into exp2; no max-sub
        // (scores ~N(0,1), 6-sigma bounded). Mask c>=60 to 0.
        #pragma unroll
        for (int nt = 0; nt < 4; ++nt) {
            float sum = 0.f;
            #pragma unroll
            for (int mt = 0; mt < 4; ++mt)
                #pragma unroll
                for (int j = 0; j < 4; ++j) {
                    float e = (mt == 3 && g == 3)
                                  ? 0.f
                                  : exp2f(acc[mt][nt][j] * 0.1803368801111137f);
                    acc[mt][nt][j] = e;
                    sum += e;
                }
            sum += __shfl_xor(sum, 16);
            sum += __shfl_xor(sum, 32);
            float inv = 1.f / sum;
            #pragma unroll
            for (int mt = 0; mt < 4; ++mt)
                #pragma unroll
                for (int j = 0; j < 4; ++j) acc[mt][nt][j] *= inv;
        }
        mk_frags<false>(pf, acc);

        // ---- v = x * WvT + bv (cols of D are features -> col-splat C-in)
        {
            float bcol[4];
            #pragma unroll
            for (int nt = 0; nt < 4; ++nt) bcol[nt] = bv[16 * nt + lo];
            GEMM(xf[t][ks], LFR(2),
                 ((f4){bcol[nt], bcol[nt], bcol[nt], bcol[nt]}));
        }
        mk_frags<false>(vf, acc);

        // ---- weightedT[d][s] = sum_c vT[d][c] P[s][c]
        GEMM(vf[t][ks], pf[t][ks], zc);
        mk_frags<false>(wtf, acc);

        // ---- h1T = relu(W1 * weightedT + b1)   (W1 pi-permuted)
        #pragma unroll
        for (int mt = 0; mt < 4; ++mt) brow[mt] = *(const f4*)&b1[16 * mt + 4 * g];
        GEMM(LFR(3), wtf[t][ks], brow[mt]);
        mk_frags<true>(h1f, acc);

        // ---- h2T = relu(W2 * h1T + b2) kept f32 in acc
        #pragma unroll
        for (int mt = 0; mt < 4; ++mt) brow[mt] = *(const f4*)&b2[16 * mt + 4 * g];
        GEMM(LFR(4), h1f[t][ks], brow[mt]);
        #pragma unroll
        for (int mt = 0; mt < 4; ++mt)
            #pragma unroll
            for (int nt = 0; nt < 4; ++nt)
                #pragma unroll
                for (int j = 0; j < 4; ++j)
                    acc[mt][nt][j] = fmaxf(acc[mt][nt][j], 0.f);

        // ---- out[s] = sum_e h2T[e][s] * W3[e] + b3
        f4 w3r[4];
        #pragma unroll
        for (int mt = 0; mt < 4; ++mt) w3r[mt] = *(const f4*)&W3[16 * mt + 4 * g];
        float b3v = b3[0];
        #pragma unroll
        for (int nt = 0; nt < 4; ++nt) {
            float sres = 0.f;
            #pragma unroll
            for (int mt = 0; mt < 4; ++mt)
                #pragma unroll
                for (int j = 0; j < 4; ++j) sres += acc[mt][nt][j] * w3r[mt][j];
            sres += __shfl_xor(sres, 16);
            sres += __shfl_xor(sres, 32);
            if (g == 0) {
                int s = 16 * nt + lo;
                if (s < 60) out[(size_t)part * 60 + s] = sres + b3v;
            }
        }
    }
}

extern "C" void kernel_launch(void* const* d_in, const int* in_sizes, int n_in,
                              void* d_out, int out_size, void* d_ws, size_t ws_size,
                              hipStream_t stream) {
    const float* x  = (const float*)d_in[0];
    const float* Wq = (const float*)d_in[1];
    const float* bq = (const float*)d_in[2];
    const float* Wk = (const float*)d_in[3];
    const float* bk = (const float*)d_in[4];
    const float* Wv = (const float*)d_in[5];
    const float* bv = (const float*)d_in[6];
    const float* W1 = (const float*)d_in[7];
    const float* b1 = (const float*)d_in[8];
    const float* W2 = (const float*)d_in[9];
    const float* b2 = (const float*)d_in[10];
    const float* W3 = (const float*)d_in[11];
    const float* b3 = (const float*)d_in[12];
    _Float16* wsH = (_Float16*)d_ws;  // 5 * 4096 halves = 40 KB

    prep_weights<<<80, 256, 0, stream>>>(Wq, Wk, Wv, W1, W2, wsH);
    // 640 WGs x 256 thr = 2560 waves; 4 parts/wave (rolled), weights in LDS,
    // sched_barrier(0) pins the back-edge against load hoisting.
    fused_f16<<<640, 256, 0, stream>>>(x, wsH, bq, bk, bv, b1, b2, W3, b3,
                                       (float*)d_out);
}

// Round 15
// 91.970 us; speedup vs baseline: 1.1005x; 1.1005x over previous
//
#include <hip/hip_runtime.h>
#include <math.h>

// B=256, P=40, S=60, D=64. Register-resident MFMA chain, weights in LDS.
// Round-15: residency from WITHIN the workgroup. Lifetime arithmetic
// R11-R14: scheduler runs ~1 WG/CU at a time (wall = (nWG/256) x WG_life);
// static VGPR/LDS caps never bound. R13 proved LDS-weights cut per-wave
// time to ~7.5 us/part but 4-wave WGs left 3 waves/CU. Fix: 1024-thread
// WGs = 16 waves = 4 waves/SIMD resident by construction; 1 part/wave
// (no rolled loop -> no liveness creep, VGPR ~124 <= 128 cap from
// __launch_bounds__(1024)); 640 WGs x 16 parts = 10240.
//
// Register-chain trick: MFMA contraction is invariant to permuting the k-dim.
// C/D output holds the row-dim in-lane as {16mt+4g+j}; the next GEMM
// contracting that dim takes both operands by pure register reindexing:
//     frag[t][ks] = pk16( acc[2ks][t], acc[2ks+1][t] )
// map pi(ks,i,g)=16*(2ks+(i>>2))+4g+(i&3). W1/W2 pre-permuted to pi-layout.
//
// Layout facts (cdna4 guide, measured m89/m91):
//   C/D: lane holds col=lane&15, rows 16mt+4(lane>>4)+j
//   A/B: row(col)=lane&15, kappa = 32ks+8(lane>>4)+i

typedef _Float16 half8 __attribute__((ext_vector_type(8)));
typedef __fp16 fp16x2 __attribute__((ext_vector_type(2)));
typedef float f4 __attribute__((ext_vector_type(4)));

#define MFMA16(a, b, c) __builtin_amdgcn_mfma_f32_16x16x32_f16((a), (b), (c), 0, 0, 0)

__global__ __launch_bounds__(256) void prep_weights(
    const float* __restrict__ Wq, const float* __restrict__ Wk,
    const float* __restrict__ Wv, const float* __restrict__ W1,
    const float* __restrict__ W2, _Float16* __restrict__ wsH) {
    int idx = blockIdx.x * 256 + threadIdx.x;  // 0..20479
    int m = idx >> 12, r = idx & 4095;
    const float* src = (m == 0) ? Wq : (m == 1) ? Wk : (m == 2) ? Wv
                        : (m == 3) ? W1 : W2;
    float v;
    if (m < 3) {
        v = src[r];  // natural row-major [e][d]
    } else {
        // pi-permuted: position (e, kappa) holds W[e][ d=16*(2ks+(i>>2))+4g+(i&3) ]
        int e = r >> 6, kp = r & 63;
        int ks = kp >> 5, gg = (kp >> 3) & 3, i = kp & 7;
        int d = 16 * (2 * ks + (i >> 2)) + 4 * gg + (i & 3);
        v = src[e * 64 + d];
    }
    wsH[idx] = (_Float16)v;
}

// Packed f32x4 + f32x4 -> half8 via v_cvt_pkrtz_f16_f32 (4 insts).
__device__ __forceinline__ half8 pk8(f4 a, f4 b) {
    union { half8 h; fp16x2 p[4]; } u;
    u.p[0] = __builtin_amdgcn_cvt_pkrtz(a[0], a[1]);
    u.p[1] = __builtin_amdgcn_cvt_pkrtz(a[2], a[3]);
    u.p[2] = __builtin_amdgcn_cvt_pkrtz(b[0], b[1]);
    u.p[3] = __builtin_amdgcn_cvt_pkrtz(b[2], b[3]);
    return u.h;
}

// acc -> pi-layout fragments (optional relu; bias already folded via C-in).
template <bool RELU>
__device__ __forceinline__ void mk_frags(half8 fr[4][2], f4 acc[4][4]) {
    #pragma unroll
    for (int t = 0; t < 4; ++t)
        #pragma unroll
        for (int ks = 0; ks < 2; ++ks) {
            f4 a = acc[2 * ks][t], b = acc[2 * ks + 1][t];
            if (RELU) {
                #pragma unroll
                for (int j = 0; j < 4; ++j) {
                    a[j] = fmaxf(a[j], 0.f);
                    b[j] = fmaxf(b[j], 0.f);
                }
            }
            fr[t][ks] = pk8(a, b);
        }
}

__device__ __forceinline__ void load_x(half8 xf[4][2], const float* __restrict__ xp,
                                       int lo, int g) {
    #pragma unroll
    for (int t = 0; t < 4; ++t) {
        int r = 16 * t + lo;
        #pragma unroll
        for (int ks = 0; ks < 2; ++ks) {
            if (r < 60) {
                const float* p = xp + r * 64 + ks * 32 + g * 8;
                xf[t][ks] = pk8(*(const f4*)p, *(const f4*)(p + 4));
            } else {
                half8 z = {};
                xf[t][ks] = z;
            }
        }
    }
}

// CEXPR is the C operand of the FIRST K-step (bias quad or zc); uses mt, nt.
#define GEMM(AEXPR, BEXPR, CEXPR)                                            \
    do {                                                                     \
        _Pragma("unroll")                                                    \
        for (int ks = 0; ks < 2; ++ks) {                                     \
            half8 afr[4], bfr[4];                                            \
            _Pragma("unroll")                                                \
            for (int t = 0; t < 4; ++t) { afr[t] = (AEXPR); bfr[t] = (BEXPR); } \
            _Pragma("unroll")                                                \
            for (int mt = 0; mt < 4; ++mt)                                   \
                _Pragma("unroll")                                            \
                for (int nt = 0; nt < 4; ++nt)                               \
                    acc[mt][nt] = MFMA16(afr[mt], bfr[nt],                   \
                                         ks == 0 ? (CEXPR) : acc[mt][nt]);   \
        }                                                                    \
    } while (0)

// LDS weight fragment read: element (row=16t+lo, kappa=32ks+8g) of matrix widx,
// 16B chunk XOR-swizzled by (lo&7)<<3 halves (row&7 == lo&7 since 16t%8==0).
#define LFR(widx) (*(const half8*)&wlds[(widx) * 4096 + (16 * t + lo) * 64 + \
                                        ((32 * ks + 8 * g) ^ ((lo & 7) << 3))])

__global__ __launch_bounds__(1024) void fused_f16(
    const float* __restrict__ x, const _Float16* __restrict__ wH,
    const float* __restrict__ bq, const float* __restrict__ bk,
    const float* __restrict__ bv, const float* __restrict__ b1,
    const float* __restrict__ b2, const float* __restrict__ W3,
    const float* __restrict__ b3, float* __restrict__ out) {
    __shared__ __align__(16) _Float16 wlds[5 * 4096];  // 40 KB

    const int tid = threadIdx.x;
    const int l = tid & 63;           // lane
    const int w = tid >> 6;           // wave 0..15 (one part each)
    const int lo = l & 15, g = l >> 4;

    // ---- cooperative weight load global->LDS with write-side swizzle:
    // dst halfidx = widx*4096 + row*64 + ((c*8) ^ ((row&7)<<3)), c = 16B chunk.
    #pragma unroll
    for (int rep = 0; rep < 3; ++rep) {
        int chunk = rep * 1024 + tid;         // 0..2559 valid
        if (chunk < 2560) {
            int widx = chunk >> 9;
            int rem = chunk & 511;
            int row = rem >> 3, c = rem & 7;
            *(half8*)&wlds[widx * 4096 + row * 64 + ((c * 8) ^ ((row & 7) << 3))] =
                *(const half8*)&wH[widx * 4096 + row * 64 + c * 8];
        }
    }
    __syncthreads();  // only barrier; 16 waves independent afterwards

    const int part = blockIdx.x * 16 + w;  // one part per wave
    const float* __restrict__ xp = x + (size_t)part * (60 * 64);
    const f4 zc = {0.f, 0.f, 0.f, 0.f};

    f4 acc[4][4];
    f4 brow[4];
    half8 xf[4][2], qf[4][2], kf[4][2], vf[4][2], pf[4][2], wtf[4][2],
          h1f[4][2];

    load_x(xf, xp, lo, g);

    // ---- qT = Wq * xT + bq (bias via C-in; rows of D are features)
    #pragma unroll
    for (int mt = 0; mt < 4; ++mt) brow[mt] = *(const f4*)&bq[16 * mt + 4 * g];
    GEMM(LFR(0), xf[t][ks], brow[mt]);
    mk_frags<false>(qf, acc);

    // ---- kT = Wk * xT + bk
    #pragma unroll
    for (int mt = 0; mt < 4; ++mt) brow[mt] = *(const f4*)&bk[16 * mt + 4 * g];
    GEMM(LFR(1), xf[t][ks], brow[mt]);
    mk_frags<false>(kf, acc);

    // ---- scoresT[c][s] = sum_d k[c][d] q[s][d]  (before v: caps liveness)
    GEMM(kf[t][ks], qf[t][ks], zc);

    // ---- softmax over c, scale 1/8 folded into exp2; no max-sub
    // (scores ~N(0,1), 6-sigma bounded -> exp safe in f32). Mask c>=60.
    #pragma unroll
    for (int nt = 0; nt < 4; ++nt) {
        float sum = 0.f;
        #pragma unroll
        for (int mt = 0; mt < 4; ++mt)
            #pragma unroll
            for (int j = 0; j < 4; ++j) {
                float e = (mt == 3 && g == 3)
                              ? 0.f
                              : exp2f(acc[mt][nt][j] * 0.1803368801111137f);
                acc[mt][nt][j] = e;
                sum += e;
            }
        sum += __shfl_xor(sum, 16);
        sum += __shfl_xor(sum, 32);
        float inv = 1.f / sum;
        #pragma unroll
        for (int mt = 0; mt < 4; ++mt)
            #pragma unroll
            for (int j = 0; j < 4; ++j) acc[mt][nt][j] *= inv;
    }
    mk_frags<false>(pf, acc);

    // ---- v = x * WvT + bv (cols of D are features -> col-splat C-in)
    {
        float bcol[4];
        #pragma unroll
        for (int nt = 0; nt < 4; ++nt) bcol[nt] = bv[16 * nt + lo];
        GEMM(xf[t][ks], LFR(2),
             ((f4){bcol[nt], bcol[nt], bcol[nt], bcol[nt]}));
    }
    mk_frags<false>(vf, acc);

    // ---- weightedT[d][s] = sum_c vT[d][c] P[s][c]
    GEMM(vf[t][ks], pf[t][ks], zc);
    mk_frags<false>(wtf, acc);

    // ---- h1T = relu(W1 * weightedT + b1)   (W1 pi-permuted)
    #pragma unroll
    for (int mt = 0; mt < 4; ++mt) brow[mt] = *(const f4*)&b1[16 * mt + 4 * g];
    GEMM(LFR(3), wtf[t][ks], brow[mt]);
    mk_frags<true>(h1f, acc);

    // ---- h2T = relu(W2 * h1T + b2) kept f32 in acc
    #pragma unroll
    for (int mt = 0; mt < 4; ++mt) brow[mt] = *(const f4*)&b2[16 * mt + 4 * g];
    GEMM(LFR(4), h1f[t][ks], brow[mt]);
    #pragma unroll
    for (int mt = 0; mt < 4; ++mt)
        #pragma unroll
        for (int nt = 0; nt < 4; ++nt)
            #pragma unroll
            for (int j = 0; j < 4; ++j)
                acc[mt][nt][j] = fmaxf(acc[mt][nt][j], 0.f);

    // ---- out[s] = sum_e h2T[e][s] * W3[e] + b3
    f4 w3r[4];
    #pragma unroll
    for (int mt = 0; mt < 4; ++mt) w3r[mt] = *(const f4*)&W3[16 * mt + 4 * g];
    float b3v = b3[0];
    #pragma unroll
    for (int nt = 0; nt < 4; ++nt) {
        float sres = 0.f;
        #pragma unroll
        for (int mt = 0; mt < 4; ++mt)
            #pragma unroll
            for (int j = 0; j < 4; ++j) sres += acc[mt][nt][j] * w3r[mt][j];
        sres += __shfl_xor(sres, 16);
        sres += __shfl_xor(sres, 32);
        if (g == 0) {
            int s = 16 * nt + lo;
            if (s < 60) out[(size_t)part * 60 + s] = sres + b3v;
        }
    }
}

extern "C" void kernel_launch(void* const* d_in, const int* in_sizes, int n_in,
                              void* d_out, int out_size, void* d_ws, size_t ws_size,
                              hipStream_t stream) {
    const float* x  = (const float*)d_in[0];
    const float* Wq = (const float*)d_in[1];
    const float* bq = (const float*)d_in[2];
    const float* Wk = (const float*)d_in[3];
    const float* bk = (const float*)d_in[4];
    const float* Wv = (const float*)d_in[5];
    const float* bv = (const float*)d_in[6];
    const float* W1 = (const float*)d_in[7];
    const float* b1 = (const float*)d_in[8];
    const float* W2 = (const float*)d_in[9];
    const float* b2 = (const float*)d_in[10];
    const float* W3 = (const float*)d_in[11];
    const float* b3 = (const float*)d_in[12];
    _Float16* wsH = (_Float16*)d_ws;  // 5 * 4096 halves = 40 KB

    prep_weights<<<80, 256, 0, stream>>>(Wq, Wk, Wv, W1, W2, wsH);
    // 640 WGs x 1024 thr = 16 waves/WG = 4 waves/SIMD by construction;
    // one part per wave; weights in LDS, amortized over 16 parts.
    fused_f16<<<640, 1024, 0, stream>>>(x, wsH, bq, bk, bv, b1, b2, W3, b3,
                                        (float*)d_out);
}